// Round 6
// baseline (590.550 us; speedup 1.0000x reference)
//
#include <hip/hip_runtime.h>

#define N_NODES 100000
#define N_PAD 100032      // padded to 64-node tiles for MFMA
#define N_EDGES 1600000
#define NUM_RELS 8
#define KDIM 256      // E_DIM * MAX_LEN
#define HD 64
#define KF 512        // fused GEMM K = NUM_RELS * 64

// CSR-build partition parameters
#define B_SHIFT 6
#define NBUCK 1568        // ceil(100000/64)=1563, padded
#define NBLK_P 256
#define TPB_P 512
#define EPB 6250          // 256 * 6250 = 1.6M exactly

typedef __attribute__((ext_vector_type(8))) short bf16x8;
typedef __attribute__((ext_vector_type(4))) float f32x4;

__device__ inline unsigned short f2bf(float f) {
    unsigned u = __float_as_uint(f);
    u += 0x7fff + ((u >> 16) & 1);   // round-to-nearest-even
    return (unsigned short)(u >> 16);
}
__device__ inline float bf2f(unsigned short s) {
    return __uint_as_float(((unsigned)s) << 16);
}
// truncating pack of two f32 -> two bf16 in one u32
__device__ inline unsigned packtrunc(float x, float y) {
    return (__float_as_uint(x) >> 16) | (__float_as_uint(y) & 0xffff0000u);
}

// ---------------- weights:
//  WpF_l: B-fragment layout over K=512: WpF[((s*4+q)*64+o)*8+j] = Wfull[kk=s*32+q*8+j][o]
//  where Wfull[r*64+k][o] = sum_b comp[r,b] V[b,k,o]
//  smPack: B-fragment layout for size matcher (K=256): smPack[((s*4+q)*64+o)*8+j] = sm_w[o][s*32+q*8+j]
__global__ void k_weights(const float* __restrict__ V1, const float* __restrict__ comp1,
                          const float* __restrict__ V2, const float* __restrict__ comp2,
                          const float* __restrict__ sm_w,
                          unsigned short* __restrict__ WpF1, unsigned short* __restrict__ WpF2,
                          unsigned short* __restrict__ smPack) {
    int idx = blockIdx.x * 256 + threadIdx.x;
    if (idx < 2 * NUM_RELS * 64 * 64) {
        int l = idx >> 15;
        int r = (idx >> 12) & 7;
        int k = (idx >> 6) & 63;
        int o = idx & 63;
        const float* V = l ? V2 : V1;
        const float* comp = l ? comp2 : comp1;
        float s = 0.f;
#pragma unroll
        for (int b = 0; b < 8; b++) s += comp[r * 8 + b] * V[(b * 64 + k) * 64 + o];
        int kk = r * 64 + k;
        int ss = kk >> 5, q = (kk >> 3) & 3, j = kk & 7;
        unsigned short* Wp = l ? WpF2 : WpF1;
        Wp[(((ss * 4 + q) * 64) + o) * 8 + j] = f2bf(s);
    } else {
        int j = idx - 65536;
        if (j < KDIM * HD) {
            int k = j >> 6, o = j & 63;
            int s = k >> 5, q = (k >> 3) & 3, jj = k & 7;
            smPack[(((s * 4 + q) * 64) + o) * 8 + jj] = f2bf(sm_w[o * KDIM + k]);
        }
    }
}

// ---------------- CSR build pass A: per-block LDS histogram over coarse buckets
__launch_bounds__(TPB_P)
__global__ void k_pcount(const int* __restrict__ dst, int* __restrict__ cnt) {
    __shared__ int lh[NBUCK];
    int t = threadIdx.x, blk = blockIdx.x;
    for (int b = t; b < NBUCK; b += TPB_P) lh[b] = 0;
    __syncthreads();
    int base = blk * EPB;
    for (int i = t; i < EPB; i += TPB_P) atomicAdd(&lh[dst[base + i] >> B_SHIFT], 1);
    __syncthreads();
    for (int b = t; b < NBUCK; b += TPB_P) cnt[blk * NBUCK + b] = lh[b];
}

// ---------------- pass B1: per-bucket exclusive scan across the NBLK_P blocks
__global__ void k_pscan(const int* __restrict__ cnt, int* __restrict__ boffm, int* __restrict__ btot) {
    __shared__ int s[NBLK_P];
    int b = blockIdx.x, t = threadIdx.x;
    int v = cnt[t * NBUCK + b];
    s[t] = v;
    __syncthreads();
    for (int off = 1; off < NBLK_P; off <<= 1) {
        int u = (t >= off) ? s[t - off] : 0;
        __syncthreads();
        s[t] += u;
        __syncthreads();
    }
    boffm[t * NBUCK + b] = s[t] - v;
    if (t == NBLK_P - 1) btot[b] = s[NBLK_P - 1];
}

// ---------------- pass B2: exclusive scan over bucket totals -> bucket starts
__global__ void k_bscan(const int* __restrict__ btot, int* __restrict__ bstart, int* __restrict__ rowptr) {
    __shared__ int s[2048];
    int t = threadIdx.x;
    int i0 = t, i1 = t + 1024;
    int v0 = (i0 < NBUCK) ? btot[i0] : 0;
    int v1 = (i1 < NBUCK) ? btot[i1] : 0;
    s[i0] = v0; s[i1] = v1;
    __syncthreads();
    for (int off = 1; off < 2048; off <<= 1) {
        int t0 = (i0 >= off) ? s[i0 - off] : 0;
        int t1 = (i1 >= off) ? s[i1 - off] : 0;
        __syncthreads();
        s[i0] += t0; s[i1] += t1;
        __syncthreads();
    }
    if (i0 < NBUCK) bstart[i0] = s[i0] - v0;
    if (i1 < NBUCK) bstart[i1] = s[i1] - v1;
    if (t == 0) rowptr[N_NODES] = N_EDGES;
}

// ---------------- pass C: scatter edges into bucket-contiguous staging
// packed = src | et<<17 | dlocal<<20
__launch_bounds__(TPB_P)
__global__ void k_pscatter(const int* __restrict__ src, const int* __restrict__ dst,
                           const int* __restrict__ et, const float* __restrict__ norm,
                           const int* __restrict__ boffm, const int* __restrict__ bstart,
                           int2* __restrict__ staged) {
    __shared__ int ldsoff[NBUCK];
    int t = threadIdx.x, blk = blockIdx.x;
    for (int b = t; b < NBUCK; b += TPB_P) ldsoff[b] = bstart[b] + boffm[blk * NBUCK + b];
    __syncthreads();
    int base = blk * EPB;
    for (int i = t; i < EPB; i += TPB_P) {
        int e = base + i;
        int d = dst[e];
        int bu = d >> B_SHIFT;
        int pos = atomicAdd(&ldsoff[bu], 1);
        int packed = src[e] | (et[e] << 17) | ((d & 63) << 20);
        staged[pos] = make_int2(packed, __float_as_int(norm[e]));
    }
}

// ---------------- pass D: per-bucket LDS hist+scan -> tickets, rowptr, final edata
__launch_bounds__(256)
__global__ void k_finalize(const int2* __restrict__ staged, const int* __restrict__ bstart,
                           const int* __restrict__ btot, int* __restrict__ rowptr,
                           int2* __restrict__ edata) {
    __shared__ int ldeg[64];
    __shared__ int lscan[64];
    int b = blockIdx.x, t = threadIdx.x;
    int base = bstart[b];
    int cnt = btot[b];
    if (t < 64) ldeg[t] = 0;
    __syncthreads();
    int2 held[8];
    int rank[8], dl[8];
    int nh = 0;
    for (int i = t; i < cnt && nh < 8; i += 256) {
        int2 ed = staged[base + i];
        int d = (ed.x >> 20) & 63;
        held[nh] = ed;
        dl[nh] = d;
        rank[nh] = atomicAdd(&ldeg[d], 1);
        nh++;
    }
    __syncthreads();
    if (t < 64) lscan[t] = ldeg[t];
    __syncthreads();
    for (int off = 1; off < 64; off <<= 1) {
        int u = (t < 64 && t >= off) ? lscan[t - off] : 0;
        __syncthreads();
        if (t < 64) lscan[t] += u;
        __syncthreads();
    }
    if (t < 64) {
        int node = (b << B_SHIFT) + t;
        if (node < N_NODES) rowptr[node] = base + lscan[t] - ldeg[t];
    }
    __syncthreads();
    for (int i = 0; i < nh; i++) {
        int d = dl[i];
        int p = base + lscan[d] - ldeg[d] + rank[i];
        edata[p] = make_int2(held[i].x & 0xFFFFF, held[i].y);   // src | et<<17
    }
}

// ---------------- size matcher (MFMA, no LDS)
__launch_bounds__(256)
__global__ void k_sizematch(const int* __restrict__ feat, const float* __restrict__ emb_w,
                            const unsigned short* __restrict__ smPack, const float* __restrict__ sm_b,
                            unsigned short* __restrict__ xb) {
    int t = threadIdx.x;
    int wave = t >> 6, lane = t & 63;
    int q = lane >> 4, c = lane & 15;
    int n0 = blockIdx.x * 64 + wave * 16;
    int node = n0 + c;
    int nclamp = (node < N_NODES) ? node : (N_NODES - 1);
    const int4* fr = (const int4*)(feat + (size_t)nclamp * 8);
    int4 f0 = fr[0], f1 = fr[1];
    int fidx[8] = {f0.x, f0.y, f0.z, f0.w, f1.x, f1.y, f1.z, f1.w};
    f32x4 acc[4];
#pragma unroll
    for (int i = 0; i < 4; i++) acc[i] = (f32x4){0.f, 0.f, 0.f, 0.f};
    const bf16x8* B8 = (const bf16x8*)smPack;
#pragma unroll
    for (int s = 0; s < 8; s++) {
        const float4* ar = (const float4*)(emb_w + (size_t)fidx[s] * 32 + q * 8);
        float4 a0 = ar[0], a1 = ar[1];
        union { unsigned u[4]; bf16x8 v; } A;
        A.u[0] = packtrunc(a0.x, a0.y);
        A.u[1] = packtrunc(a0.z, a0.w);
        A.u[2] = packtrunc(a1.x, a1.y);
        A.u[3] = packtrunc(a1.z, a1.w);
#pragma unroll
        for (int tl = 0; tl < 4; tl++) {
            bf16x8 b = B8[(s * 4 + q) * 64 + tl * 16 + c];
            acc[tl] = __builtin_amdgcn_mfma_f32_16x16x32_bf16(A.v, b, acc[tl], 0, 0, 0);
        }
    }
    int row_base = n0 + q * 4;
    bool full = (n0 + 15 < N_NODES);
#pragma unroll
    for (int tl = 0; tl < 4; tl++) {
        int o = tl * 16 + c;
        float bia = sm_b[o];
#pragma unroll
        for (int r = 0; r < 4; r++) {
            int nd = row_base + r;
            if (full || nd < N_NODES)
                xb[(size_t)nd * 64 + o] = f2bf(acc[tl][r] + bia);
        }
    }
}

// ---------------- fused layer: aggregate in x-space (LDS agg[32][512]) then MFMA @ Wfull
// block: 256 thr = 4 waves, 32 nodes (8/wave). mode: 1 = relu+bf16 out, 0 = f32 out.
__launch_bounds__(256)
__global__ void k_fused(const unsigned short* __restrict__ xin,
                        const int* __restrict__ rowptr, const int2* __restrict__ edata,
                        const unsigned short* __restrict__ WpF, const float* __restrict__ bias,
                        float* __restrict__ outf, unsigned short* __restrict__ outb, int mode) {
    __shared__ unsigned short agg[32 * 520];   // +8 bf16 pad per row -> conflict-light
    int t = threadIdx.x;
    int wave = t >> 6, lane = t & 63;
    int es = lane >> 4, c = lane & 15;
    int n0 = blockIdx.x * 32;
    {
        int* a4 = (int*)agg;
        for (int i = t; i < 32 * 260; i += 256) a4[i] = 0;
    }
    __syncthreads();
    // ---- aggregation: 8 nodes per wave, 4 edge slots, ushort4 channels per lane
    for (int ni = 0; ni < 8; ni++) {
        int node = n0 + wave * 8 + ni;
        int j0 = rowptr[node], j1 = rowptr[node + 1];
        float acc[8][4];
#pragma unroll
        for (int r = 0; r < 8; r++)
#pragma unroll
            for (int i = 0; i < 4; i++) acc[r][i] = 0.f;
        for (int j = j0 + es; j < j1; j += 4) {
            int2 ed = edata[j];
            int srcv = ed.x & 0x1FFFF;
            int et = (ed.x >> 17) & 7;
            float nn = __int_as_float(ed.y);
            ushort4 v = *(const ushort4*)(xin + ((size_t)srcv << 6) + c * 4);
            float x0 = bf2f(v.x), x1 = bf2f(v.y), x2 = bf2f(v.z), x3 = bf2f(v.w);
#pragma unroll
            for (int r = 0; r < 8; r++) {
                float sel = (et == r) ? nn : 0.f;
                acc[r][0] += sel * x0;
                acc[r][1] += sel * x1;
                acc[r][2] += sel * x2;
                acc[r][3] += sel * x3;
            }
        }
#pragma unroll
        for (int r = 0; r < 8; r++)
#pragma unroll
            for (int i = 0; i < 4; i++) {
                acc[r][i] += __shfl_xor(acc[r][i], 16);
                acc[r][i] += __shfl_xor(acc[r][i], 32);
            }
        int lrow = wave * 8 + ni;
#pragma unroll
        for (int rr = 0; rr < 2; rr++) {
            int r = es * 2 + rr;
            ushort4 pk = make_ushort4(f2bf(acc[r][0]), f2bf(acc[r][1]),
                                      f2bf(acc[r][2]), f2bf(acc[r][3]));
            *(ushort4*)&agg[lrow * 520 + r * 64 + c * 4] = pk;
        }
    }
    __syncthreads();
    // ---- GEMM: [32 x 512] @ WpF (512 x 64); wave -> out cols [wave*16, wave*16+16)
    int q = es;
    int o16 = wave * 16;
    f32x4 accd[2];
    accd[0] = (f32x4){0.f, 0.f, 0.f, 0.f};
    accd[1] = (f32x4){0.f, 0.f, 0.f, 0.f};
    const bf16x8* B8 = (const bf16x8*)WpF;
#pragma unroll
    for (int s = 0; s < 16; s++) {
        bf16x8 b = B8[(s * 4 + q) * 64 + o16 + c];
        bf16x8 a0 = *(const bf16x8*)&agg[(0 * 16 + c) * 520 + s * 32 + q * 8];
        bf16x8 a1 = *(const bf16x8*)&agg[(1 * 16 + c) * 520 + s * 32 + q * 8];
        accd[0] = __builtin_amdgcn_mfma_f32_16x16x32_bf16(a0, b, accd[0], 0, 0, 0);
        accd[1] = __builtin_amdgcn_mfma_f32_16x16x32_bf16(a1, b, accd[1], 0, 0, 0);
    }
    int col = o16 + c;
    float bia = bias[col];
#pragma unroll
    for (int t2 = 0; t2 < 2; t2++) {
#pragma unroll
        for (int r = 0; r < 4; r++) {
            int node = n0 + t2 * 16 + q * 4 + r;
            float v = accd[t2][r] + bia;
            if (mode == 1) {
                v = fmaxf(v, 0.f);
                outb[(size_t)node * 64 + col] = f2bf(v);
            } else {
                outf[(size_t)node * 64 + col] = v;
            }
        }
    }
}

extern "C" void kernel_launch(void* const* d_in, const int* in_sizes, int n_in,
                              void* d_out, int out_size, void* d_ws, size_t ws_size,
                              hipStream_t stream) {
    const int*   feat  = (const int*)d_in[0];
    const int*   src   = (const int*)d_in[1];
    const int*   dst   = (const int*)d_in[2];
    const int*   etype = (const int*)d_in[3];
    const float* norm  = (const float*)d_in[4];
    const float* emb_w = (const float*)d_in[5];
    const float* sm_w  = (const float*)d_in[6];
    const float* sm_b  = (const float*)d_in[7];
    const float* V1    = (const float*)d_in[8];
    const float* comp1 = (const float*)d_in[9];
    const float* b1    = (const float*)d_in[10];
    const float* V2    = (const float*)d_in[11];
    const float* comp2 = (const float*)d_in[12];
    const float* b2    = (const float*)d_in[13];
    float* out = (float*)d_out;

    char* p = (char*)d_ws;
    auto alloc = [&](size_t bytes) { void* q = (void*)p; p += (bytes + 255) & ~(size_t)255; return q; };
    unsigned short* xb   = (unsigned short*)alloc((size_t)N_PAD * 64 * 2);  // 12.8 MB
    unsigned short* hb   = (unsigned short*)alloc((size_t)N_PAD * 64 * 2);  // 12.8 MB
    unsigned short* WpF1 = (unsigned short*)alloc((size_t)KF * HD * 2);     // 64 KB
    unsigned short* WpF2 = (unsigned short*)alloc((size_t)KF * HD * 2);
    unsigned short* smPack = (unsigned short*)alloc(KDIM * HD * 2);         // 32 KB
    int*   cnt    = (int*)alloc((size_t)NBLK_P * NBUCK * 4);                // 1.6 MB
    int*   boffm  = (int*)alloc((size_t)NBLK_P * NBUCK * 4);                // 1.6 MB
    int*   btot   = (int*)alloc((size_t)NBUCK * 4);
    int*   bstart = (int*)alloc((size_t)NBUCK * 4);
    int*   rowptr = (int*)alloc(((size_t)N_NODES + 1) * 4);
    int2*  staged = (int2*)alloc((size_t)N_EDGES * 8);                      // 12.8 MB
    int2*  edata  = (int2*)alloc((size_t)N_EDGES * 8);                      // 12.8 MB

    k_weights<<<320, 256, 0, stream>>>(V1, comp1, V2, comp2, sm_w, WpF1, WpF2, smPack);

    k_pcount<<<NBLK_P, TPB_P, 0, stream>>>(dst, cnt);
    k_pscan<<<NBUCK, NBLK_P, 0, stream>>>(cnt, boffm, btot);
    k_bscan<<<1, 1024, 0, stream>>>(btot, bstart, rowptr);
    k_pscatter<<<NBLK_P, TPB_P, 0, stream>>>(src, dst, etype, norm, boffm, bstart, staged);
    k_finalize<<<NBUCK, 256, 0, stream>>>(staged, bstart, btot, rowptr, edata);

    k_sizematch<<<N_PAD / 64, 256, 0, stream>>>(feat, emb_w, smPack, sm_b, xb);

    k_fused<<<N_NODES / 32, 256, 0, stream>>>(xb, rowptr, edata, WpF1, b1, nullptr, hb, 1);
    k_fused<<<N_NODES / 32, 256, 0, stream>>>(hb, rowptr, edata, WpF2, b2, out, nullptr, 0);
}

// Round 7
// 386.531 us; speedup vs baseline: 1.5278x; 1.5278x over previous
//
#include <hip/hip_runtime.h>

#define N_NODES 100000
#define N_PAD 100032      // padded to 64-node tiles for MFMA sizematch
#define N_EDGES 1600000
#define NUM_RELS 8
#define KDIM 256      // E_DIM * MAX_LEN
#define HD 64
#define KF 512        // fused GEMM K = NUM_RELS * 64

// CSR-build partition parameters
#define B_SHIFT 6
#define NBUCK 1568        // ceil(100000/64)=1563, padded
#define NBLK_P 512
#define TPB_P 256
#define EPB 3125          // 512 * 3125 = 1.6M exactly

typedef __attribute__((ext_vector_type(8))) short bf16x8;
typedef __attribute__((ext_vector_type(4))) float f32x4;

__device__ inline unsigned short f2bf(float f) {
    unsigned u = __float_as_uint(f);
    u += 0x7fff + ((u >> 16) & 1);   // round-to-nearest-even
    return (unsigned short)(u >> 16);
}
__device__ inline float bf2f(unsigned short s) {
    return __uint_as_float(((unsigned)s) << 16);
}
// truncating pack of two f32 -> two bf16 in one u32
__device__ inline unsigned packtrunc(float x, float y) {
    return (__float_as_uint(x) >> 16) | (__float_as_uint(y) & 0xffff0000u);
}

// ---------------- weights:
//  WpF_l: B-fragment layout over K=512: WpF[((s*4+q)*64+o)*8+j] = Wfull[kk=s*32+q*8+j][o]
//  where Wfull[r*64+k][o] = sum_b comp[r,b] V[b,k,o]
//  smPack: B-fragment layout for size matcher (K=256)
__global__ void k_weights(const float* __restrict__ V1, const float* __restrict__ comp1,
                          const float* __restrict__ V2, const float* __restrict__ comp2,
                          const float* __restrict__ sm_w,
                          unsigned short* __restrict__ WpF1, unsigned short* __restrict__ WpF2,
                          unsigned short* __restrict__ smPack) {
    int idx = blockIdx.x * 256 + threadIdx.x;
    if (idx < 2 * NUM_RELS * 64 * 64) {
        int l = idx >> 15;
        int r = (idx >> 12) & 7;
        int k = (idx >> 6) & 63;
        int o = idx & 63;
        const float* V = l ? V2 : V1;
        const float* comp = l ? comp2 : comp1;
        float s = 0.f;
#pragma unroll
        for (int b = 0; b < 8; b++) s += comp[r * 8 + b] * V[(b * 64 + k) * 64 + o];
        int kk = r * 64 + k;
        int ss = kk >> 5, q = (kk >> 3) & 3, j = kk & 7;
        unsigned short* Wp = l ? WpF2 : WpF1;
        Wp[(((ss * 4 + q) * 64) + o) * 8 + j] = f2bf(s);
    } else {
        int j = idx - 65536;
        if (j < KDIM * HD) {
            int k = j >> 6, o = j & 63;
            int s = k >> 5, q = (k >> 3) & 3, jj = k & 7;
            smPack[(((s * 4 + q) * 64) + o) * 8 + jj] = f2bf(sm_w[o * KDIM + k]);
        }
    }
}

// ---------------- CSR build pass A: per-block LDS histogram over coarse buckets
__launch_bounds__(TPB_P)
__global__ void k_pcount(const int* __restrict__ dst, int* __restrict__ cnt) {
    __shared__ int lh[NBUCK];
    int t = threadIdx.x, blk = blockIdx.x;
    for (int b = t; b < NBUCK; b += TPB_P) lh[b] = 0;
    __syncthreads();
    int base = blk * EPB;
    for (int i = t; i < EPB; i += TPB_P) atomicAdd(&lh[dst[base + i] >> B_SHIFT], 1);
    __syncthreads();
    for (int b = t; b < NBUCK; b += TPB_P) cnt[blk * NBUCK + b] = lh[b];
}

// ---------------- pass B1: per-bucket exclusive scan across the NBLK_P blocks
__global__ void k_pscan(const int* __restrict__ cnt, int* __restrict__ boffm, int* __restrict__ btot) {
    __shared__ int s[NBLK_P];
    int b = blockIdx.x, t = threadIdx.x;
    int v = cnt[t * NBUCK + b];
    s[t] = v;
    __syncthreads();
    for (int off = 1; off < NBLK_P; off <<= 1) {
        int u = (t >= off) ? s[t - off] : 0;
        __syncthreads();
        s[t] += u;
        __syncthreads();
    }
    boffm[t * NBUCK + b] = s[t] - v;
    if (t == NBLK_P - 1) btot[b] = s[NBLK_P - 1];
}

// ---------------- pass B2: exclusive scan over bucket totals -> bucket starts
__global__ void k_bscan(const int* __restrict__ btot, int* __restrict__ bstart, int* __restrict__ rowptr) {
    __shared__ int s[2048];
    int t = threadIdx.x;
    int i0 = t, i1 = t + 1024;
    int v0 = (i0 < NBUCK) ? btot[i0] : 0;
    int v1 = (i1 < NBUCK) ? btot[i1] : 0;
    s[i0] = v0; s[i1] = v1;
    __syncthreads();
    for (int off = 1; off < 2048; off <<= 1) {
        int t0 = (i0 >= off) ? s[i0 - off] : 0;
        int t1 = (i1 >= off) ? s[i1 - off] : 0;
        __syncthreads();
        s[i0] += t0; s[i1] += t1;
        __syncthreads();
    }
    if (i0 < NBUCK) bstart[i0] = s[i0] - v0;
    if (i1 < NBUCK) bstart[i1] = s[i1] - v1;
    if (t == 0) rowptr[N_NODES] = N_EDGES;
}

// ---------------- pass C: scatter edges into bucket-contiguous staging
// packed = src | et<<17 | dlocal<<20  (so (packed>>17)&511 == dlocal*8+et, the sort key)
__launch_bounds__(TPB_P)
__global__ void k_pscatter(const int* __restrict__ src, const int* __restrict__ dst,
                           const int* __restrict__ et, const float* __restrict__ norm,
                           const int* __restrict__ boffm, const int* __restrict__ bstart,
                           int2* __restrict__ staged) {
    __shared__ int ldsoff[NBUCK];
    int t = threadIdx.x, blk = blockIdx.x;
    for (int b = t; b < NBUCK; b += TPB_P) ldsoff[b] = bstart[b] + boffm[blk * NBUCK + b];
    __syncthreads();
    int base = blk * EPB;
    for (int i = t; i < EPB; i += TPB_P) {
        int e = base + i;
        int d = dst[e];
        int bu = d >> B_SHIFT;
        int pos = atomicAdd(&ldsoff[bu], 1);
        int packed = src[e] | (et[e] << 17) | ((d & 63) << 20);
        staged[pos] = make_int2(packed, __float_as_int(norm[e]));
    }
}

// ---------------- pass D: per-bucket 512-bin counting sort by (dlocal, et) -> rowptr + sorted edata
__launch_bounds__(256)
__global__ void k_finalize(const int2* __restrict__ staged, const int* __restrict__ bstart,
                           const int* __restrict__ btot, int* __restrict__ rowptr,
                           int2* __restrict__ edata) {
    __shared__ int lh[512];
    __shared__ int lsc[512];
    int b = blockIdx.x, t = threadIdx.x;
    int base = bstart[b];
    int cnt = btot[b];
    lh[t] = 0; lh[t + 256] = 0;
    __syncthreads();
    int2 held[8];
    int key[8], rank[8];
    int nh = 0;
    for (int i = t; i < cnt; i += 256) {
        int2 ed = staged[base + i];
        int k = (ed.x >> 17) & 511;
        if (nh < 8) { held[nh] = ed; key[nh] = k; rank[nh] = atomicAdd(&lh[k], 1); nh++; }
    }
    __syncthreads();
    int i0 = t, i1 = t + 256;
    lsc[i0] = lh[i0]; lsc[i1] = lh[i1];
    __syncthreads();
    for (int off = 1; off < 512; off <<= 1) {
        int u0 = (i0 >= off) ? lsc[i0 - off] : 0;
        int u1 = (i1 >= off) ? lsc[i1 - off] : 0;
        __syncthreads();
        lsc[i0] += u0; lsc[i1] += u1;
        __syncthreads();
    }
    if (t < 64) {
        int node = (b << B_SHIFT) + t;
        if (node < N_NODES) rowptr[node] = base + lsc[t * 8] - lh[t * 8];
    }
    for (int i = 0; i < nh; i++) {
        int k = key[i];
        int p = base + lsc[k] - lh[k] + rank[i];
        edata[p] = held[i];
    }
}

// ---------------- size matcher (MFMA, no LDS)
__launch_bounds__(256)
__global__ void k_sizematch(const int* __restrict__ feat, const float* __restrict__ emb_w,
                            const unsigned short* __restrict__ smPack, const float* __restrict__ sm_b,
                            unsigned short* __restrict__ xb) {
    int t = threadIdx.x;
    int wave = t >> 6, lane = t & 63;
    int q = lane >> 4, c = lane & 15;
    int n0 = blockIdx.x * 64 + wave * 16;
    int node = n0 + c;
    int nclamp = (node < N_NODES) ? node : (N_NODES - 1);
    const int4* fr = (const int4*)(feat + (size_t)nclamp * 8);
    int4 f0 = fr[0], f1 = fr[1];
    int fidx[8] = {f0.x, f0.y, f0.z, f0.w, f1.x, f1.y, f1.z, f1.w};
    f32x4 acc[4];
#pragma unroll
    for (int i = 0; i < 4; i++) acc[i] = (f32x4){0.f, 0.f, 0.f, 0.f};
    const bf16x8* B8 = (const bf16x8*)smPack;
#pragma unroll
    for (int s = 0; s < 8; s++) {
        const float4* ar = (const float4*)(emb_w + (size_t)fidx[s] * 32 + q * 8);
        float4 a0 = ar[0], a1 = ar[1];
        union { unsigned u[4]; bf16x8 v; } A;
        A.u[0] = packtrunc(a0.x, a0.y);
        A.u[1] = packtrunc(a0.z, a0.w);
        A.u[2] = packtrunc(a1.x, a1.y);
        A.u[3] = packtrunc(a1.z, a1.w);
#pragma unroll
        for (int tl = 0; tl < 4; tl++) {
            bf16x8 b = B8[(s * 4 + q) * 64 + tl * 16 + c];
            acc[tl] = __builtin_amdgcn_mfma_f32_16x16x32_bf16(A.v, b, acc[tl], 0, 0, 0);
        }
    }
    int row_base = n0 + q * 4;
    bool full = (n0 + 15 < N_NODES);
#pragma unroll
    for (int tl = 0; tl < 4; tl++) {
        int o = tl * 16 + c;
        float bia = sm_b[o];
#pragma unroll
        for (int r = 0; r < 4; r++) {
            int nd = row_base + r;
            if (full || nd < N_NODES)
                xb[(size_t)nd * 64 + o] = f2bf(acc[tl][r] + bia);
        }
    }
}

// ---------------- fused layer: rel-sorted aggregation (wave/node, lane=channel) + MFMA
// block: 256 thr = 4 waves; 16 nodes/block (4 per wave); grid N_NODES/16.
__launch_bounds__(256)
__global__ void k_fused(const unsigned short* __restrict__ xin,
                        const int* __restrict__ rowptr, const int2* __restrict__ edata,
                        const unsigned short* __restrict__ WpF, const float* __restrict__ bias,
                        float* __restrict__ outf, unsigned short* __restrict__ outb, int mode) {
    __shared__ __align__(16) unsigned short agg[16 * 520];
    int t = threadIdx.x;
    int wave = t >> 6, lane = t & 63;
    int n0 = blockIdx.x * 16;
    {
        int* a4 = (int*)agg;
        for (int i = t; i < 16 * 260; i += 256) a4[i] = 0;
    }
    __syncthreads();
    // ---- aggregation: edges sorted by (node, rel); flush on rel change
    for (int ni = 0; ni < 4; ni++) {
        int lrow = wave * 4 + ni;
        int node = n0 + lrow;
        int j0 = rowptr[node], j1 = rowptr[node + 1];
        float acc = 0.f;
        int curR = 0;
        int j = j0;
        for (; j + 4 <= j1; j += 4) {
            int2 e0 = edata[j], e1 = edata[j + 1], e2 = edata[j + 2], e3 = edata[j + 3];
            float v0 = bf2f(xin[((size_t)(e0.x & 0x1FFFF) << 6) + lane]);
            float v1 = bf2f(xin[((size_t)(e1.x & 0x1FFFF) << 6) + lane]);
            float v2 = bf2f(xin[((size_t)(e2.x & 0x1FFFF) << 6) + lane]);
            float v3 = bf2f(xin[((size_t)(e3.x & 0x1FFFF) << 6) + lane]);
            int ex[4] = {e0.x, e1.x, e2.x, e3.x};
            int ey[4] = {e0.y, e1.y, e2.y, e3.y};
            float vv[4] = {v0, v1, v2, v3};
#pragma unroll
            for (int s2 = 0; s2 < 4; s2++) {
                int et = (ex[s2] >> 17) & 7;
                if (et != curR) {
                    agg[lrow * 520 + curR * 64 + lane] = f2bf(acc);
                    acc = 0.f;
                    curR = et;
                }
                acc += __int_as_float(ey[s2]) * vv[s2];
            }
        }
        for (; j < j1; j++) {
            int2 e = edata[j];
            float v = bf2f(xin[((size_t)(e.x & 0x1FFFF) << 6) + lane]);
            int et = (e.x >> 17) & 7;
            if (et != curR) {
                agg[lrow * 520 + curR * 64 + lane] = f2bf(acc);
                acc = 0.f;
                curR = et;
            }
            acc += __int_as_float(e.y) * v;
        }
        agg[lrow * 520 + curR * 64 + lane] = f2bf(acc);
    }
    __syncthreads();
    // ---- MFMA: [16 nodes x 512] @ WpF -> 64 outs; wave covers cols [wave*16, +16)
    int q = lane >> 4, c = lane & 15;
    int o16 = wave * 16;
    f32x4 accd = (f32x4){0.f, 0.f, 0.f, 0.f};
    const bf16x8* B8 = (const bf16x8*)WpF;
#pragma unroll
    for (int s = 0; s < 16; s++) {
        bf16x8 a = *(const bf16x8*)&agg[c * 520 + s * 32 + q * 8];
        bf16x8 bfr = B8[(s * 4 + q) * 64 + o16 + c];
        accd = __builtin_amdgcn_mfma_f32_16x16x32_bf16(a, bfr, accd, 0, 0, 0);
    }
    int col = o16 + c;
    float bia = bias[col];
#pragma unroll
    for (int r = 0; r < 4; r++) {
        int node = n0 + q * 4 + r;
        float v = accd[r] + bia;
        if (mode == 1) {
            v = fmaxf(v, 0.f);
            outb[(size_t)node * 64 + col] = f2bf(v);
        } else {
            outf[(size_t)node * 64 + col] = v;
        }
    }
}

extern "C" void kernel_launch(void* const* d_in, const int* in_sizes, int n_in,
                              void* d_out, int out_size, void* d_ws, size_t ws_size,
                              hipStream_t stream) {
    const int*   feat  = (const int*)d_in[0];
    const int*   src   = (const int*)d_in[1];
    const int*   dst   = (const int*)d_in[2];
    const int*   etype = (const int*)d_in[3];
    const float* norm  = (const float*)d_in[4];
    const float* emb_w = (const float*)d_in[5];
    const float* sm_w  = (const float*)d_in[6];
    const float* sm_b  = (const float*)d_in[7];
    const float* V1    = (const float*)d_in[8];
    const float* comp1 = (const float*)d_in[9];
    const float* b1    = (const float*)d_in[10];
    const float* V2    = (const float*)d_in[11];
    const float* comp2 = (const float*)d_in[12];
    const float* b2    = (const float*)d_in[13];
    float* out = (float*)d_out;

    char* p = (char*)d_ws;
    auto alloc = [&](size_t bytes) { void* q = (void*)p; p += (bytes + 255) & ~(size_t)255; return q; };
    unsigned short* xb   = (unsigned short*)alloc((size_t)N_PAD * 64 * 2);  // 12.8 MB
    unsigned short* hb   = (unsigned short*)alloc((size_t)N_PAD * 64 * 2);  // 12.8 MB
    unsigned short* WpF1 = (unsigned short*)alloc((size_t)KF * HD * 2);     // 64 KB
    unsigned short* WpF2 = (unsigned short*)alloc((size_t)KF * HD * 2);
    unsigned short* smPack = (unsigned short*)alloc(KDIM * HD * 2);         // 32 KB
    int*   cnt    = (int*)alloc((size_t)NBLK_P * NBUCK * 4);                // 3.2 MB
    int*   boffm  = (int*)alloc((size_t)NBLK_P * NBUCK * 4);                // 3.2 MB
    int*   btot   = (int*)alloc((size_t)NBUCK * 4);
    int*   bstart = (int*)alloc((size_t)NBUCK * 4);
    int*   rowptr = (int*)alloc(((size_t)N_NODES + 1) * 4);
    int2*  staged = (int2*)alloc((size_t)N_EDGES * 8);                      // 12.8 MB
    int2*  edata  = (int2*)alloc((size_t)N_EDGES * 8);                      // 12.8 MB

    k_weights<<<320, 256, 0, stream>>>(V1, comp1, V2, comp2, sm_w, WpF1, WpF2, smPack);

    k_pcount<<<NBLK_P, TPB_P, 0, stream>>>(dst, cnt);
    k_pscan<<<NBUCK, NBLK_P, 0, stream>>>(cnt, boffm, btot);
    k_bscan<<<1, 1024, 0, stream>>>(btot, bstart, rowptr);
    k_pscatter<<<NBLK_P, TPB_P, 0, stream>>>(src, dst, etype, norm, boffm, bstart, staged);
    k_finalize<<<NBUCK, 256, 0, stream>>>(staged, bstart, btot, rowptr, edata);

    k_sizematch<<<N_PAD / 64, 256, 0, stream>>>(feat, emb_w, smPack, sm_b, xb);

    k_fused<<<N_NODES / 16, 256, 0, stream>>>(xb, rowptr, edata, WpF1, b1, nullptr, hb, 1);
    k_fused<<<N_NODES / 16, 256, 0, stream>>>(hb, rowptr, edata, WpF2, b2, out, nullptr, 0);
}